// Round 8
// baseline (144.071 us; speedup 1.0000x reference)
//
#include <hip/hip_runtime.h>
#include <hip/hip_bf16.h>

// ChannelDeAttention: B=64,S=512,C=256,H=128,P=512
// bf16 MFMA (16x16x32), fp32 accum. 7 launches. XOR-swizzled LDS,
// 2-phase double-buffered GEMMs. Fused weight product WVO = wv@wo kills the
// batched v-GEMM: out = attn@(x^T@WVO) + rowsum(attn)⊗(bv@wo) + bo.

typedef __attribute__((ext_vector_type(8))) short bf16x8;
typedef __attribute__((ext_vector_type(4))) float f32x4;
typedef __attribute__((ext_vector_type(8))) unsigned short ushort8;

typedef __attribute__((address_space(1))) void* as1vp;
typedef __attribute__((address_space(3))) void* as3vp;

__device__ __forceinline__ void gl2lds16(const void* g, void* l) {
  __builtin_amdgcn_global_load_lds((as1vp)(void*)g, (as3vp)l, 16, 0, 0);
}

__device__ __forceinline__ float bf2f(unsigned short u) {
  union { unsigned int i; float f; } v; v.i = ((unsigned int)u) << 16; return v.f;
}
__device__ __forceinline__ unsigned short f2bf(float f) {
  union { float f; unsigned int i; } v; v.f = f;
  unsigned int r = v.i + 0x7FFFu + ((v.i >> 16) & 1u);
  return (unsigned short)(r >> 16);
}

// ------- transposes (x + 5 weight mats) + plain wv cast + bvo matvec, one launch ----
__global__ void __launch_bounds__(256) tcast_all(
    const float* __restrict__ x,
    const float* __restrict__ wq1, const float* __restrict__ wk1,
    const float* __restrict__ wq2, const float* __restrict__ wk2,
    const float* __restrict__ wq3, const float* __restrict__ wk3,
    const float* __restrict__ wv, const float* __restrict__ wo,
    const float* __restrict__ bv,
    unsigned short* __restrict__ XT,
    unsigned short* __restrict__ W1, unsigned short* __restrict__ W2,
    unsigned short* __restrict__ W3, unsigned short* __restrict__ WVNT,
    unsigned short* __restrict__ WOT, float* __restrict__ BVO) {
  const int bid = blockIdx.x;
  const int t = threadIdx.x;
  // plain-cast wv (row-major bf16) and bvo matvec blocks: no LDS path
  if (bid >= 2168) {
    if (bid < 2296) {
      long i0 = (long)(bid - 2168) * 2048 + t * 8;
      f32x4 a = *(const f32x4*)(wv + i0);
      f32x4 b = *(const f32x4*)(wv + i0 + 4);
      ushort8 o;
#pragma unroll
      for (int j = 0; j < 4; ++j) { o[j] = f2bf(a[j]); o[4 + j] = f2bf(b[j]); }
      *(ushort8*)(WVNT + i0) = o;
    } else {
      int p = (bid - 2296) * 256 + t;
      float s = 0.0f;
#pragma unroll 8
      for (int tt = 0; tt < 512; ++tt) s += bv[tt] * wo[tt * 512 + p];
      BVO[p] = s;
    }
    return;
  }
  __shared__ float lds[64][65];
  const float* S; unsigned short* D; int R, Cc, r0, c0, rowoff = 0;
  if (bid < 2048) {
    int bz = bid >> 5, i = bid & 31;
    S = x + (long)bz * 131072; D = XT + (long)bz * 131072;
    R = 512; Cc = 256; r0 = (i & 7) * 64; c0 = (i >> 3) * 64;
  } else {
    int wb = bid - 2048;
    if (wb < 32) {
      int m = wb >> 4, i = wb & 15;
      S = m ? wk1 : wq1; D = W1; R = 512; Cc = 128;
      r0 = (i & 7) * 64; c0 = (i >> 3) * 64; rowoff = m * 128;
    } else if (wb < 48) {
      int m = (wb - 32) >> 3, i = (wb - 32) & 7;
      S = m ? wk2 : wq2; D = W2; R = 256; Cc = 128;
      r0 = (i & 3) * 64; c0 = (i >> 2) * 64; rowoff = m * 128;
    } else if (wb < 56) {
      int m = (wb - 48) >> 2, i = (wb - 48) & 3;
      S = m ? wk3 : wq3; D = W3; R = 128; Cc = 128;
      r0 = (i & 1) * 64; c0 = (i >> 1) * 64; rowoff = m * 128;
    } else {
      int i = wb - 56; S = wo; D = WOT; R = 512; Cc = 512;
      r0 = (i & 7) * 64; c0 = (i >> 3) * 64;
    }
  }
  const int c = t & 63, rbase = (t >> 6) * 16;
#pragma unroll
  for (int i = 0; i < 16; ++i)
    lds[rbase + i][c] = S[(long)(r0 + rbase + i) * Cc + c0 + c];
  __syncthreads();
  const int rr = (t & 31) * 2, ccb = t >> 5;
#pragma unroll
  for (int j = 0; j < 8; ++j) {
    int cc = ccb + j * 8;
    unsigned int u0 = f2bf(lds[rr][cc]);
    unsigned int u1 = f2bf(lds[rr + 1][cc]);
    *(unsigned int*)(D + (long)(c0 + cc + rowoff) * R + r0 + rr) = u0 | (u1 << 16);
  }
}

// ------- fused Q/K projections, 8 waves, BM=128 BN=256, swizzled, dbuf (unchanged) --
__global__ void __launch_bounds__(512) proj_all8(
    const unsigned short* __restrict__ XT,
    const unsigned short* __restrict__ W1, const unsigned short* __restrict__ W2,
    const unsigned short* __restrict__ W3,
    unsigned short* __restrict__ Q1, unsigned short* __restrict__ Q2,
    unsigned short* __restrict__ Q3,
    const float* __restrict__ bq1, const float* __restrict__ bk1,
    const float* __restrict__ bq2, const float* __restrict__ bk2,
    const float* __restrict__ bq3, const float* __restrict__ bk3) {
  extern __shared__ char smem[];
  const int z = blockIdx.z;
  const unsigned short* Ab; const unsigned short* Bw; unsigned short* O;
  const float *bq, *bk; int K;
  if (z < 64) {
    K = 512; Bw = W1; O = Q1 + (long)z * 65536; bq = bq1; bk = bk1;
    Ab = XT + (long)z * 131072;
  } else if (z < 192) {
    int u = z - 64; K = 256; Bw = W2; O = Q2 + (long)u * 65536; bq = bq2; bk = bk2;
    Ab = XT + (long)(u >> 1) * 131072 + (u & 1) * 256;
  } else {
    int u = z - 192; K = 128; Bw = W3; O = Q3 + (long)u * 65536; bq = bq3; bk = bk3;
    Ab = XT + (long)(u >> 2) * 131072 + (u & 3) * 128;
  }
  const int t = threadIdx.x, lane = t & 63, wid = t >> 6;
  const int wmb = (wid >> 2) * 64, wnb = (wid & 3) * 64;
  const int m0 = blockIdx.y * 128;
  Ab += (long)m0 * 512;
  const int srow = t >> 3, ssl = t & 7;

  auto stage = [&](int buf, int k0) {
    char* s = smem + buf * 49152;
#pragma unroll
    for (int i = 0; i < 2; ++i) {
      int row = i * 64 + srow;
      gl2lds16(Ab + (long)row * 512 + k0 + (ssl ^ (row & 7)) * 8, s + i * 8192 + t * 16);
    }
#pragma unroll
    for (int i = 0; i < 4; ++i) {
      int row = i * 64 + srow;
      gl2lds16(Bw + (long)row * K + k0 + (ssl ^ (row & 7)) * 8, s + 16384 + i * 8192 + t * 16);
    }
  };

  f32x4 acc[4][4] = {};
  stage(0, 0);
  __syncthreads();
  int cur = 0;
  for (int k0 = 0; k0 < K; k0 += 64) {
    if (k0 + 64 < K) stage(cur ^ 1, k0 + 64);
    const char* s = smem + cur * 49152;
#pragma unroll
    for (int kk = 0; kk < 2; ++kk) {
      const int slot = kk * 4 + (lane >> 4);
      bf16x8 af[4], bfr[4];
#pragma unroll
      for (int mi = 0; mi < 4; ++mi) {
        int row = wmb + mi * 16 + (lane & 15);
        af[mi] = *(const bf16x8*)(s + row * 128 + 16 * (slot ^ (row & 7)));
      }
#pragma unroll
      for (int ni = 0; ni < 4; ++ni) {
        int row = wnb + ni * 16 + (lane & 15);
        bfr[ni] = *(const bf16x8*)(s + 16384 + row * 128 + 16 * (slot ^ (row & 7)));
      }
#pragma unroll
      for (int mi = 0; mi < 4; ++mi)
#pragma unroll
        for (int ni = 0; ni < 4; ++ni)
          acc[mi][ni] = __builtin_amdgcn_mfma_f32_16x16x32_bf16(af[mi], bfr[ni], acc[mi][ni], 0, 0, 0);
    }
    __syncthreads();
    cur ^= 1;
  }
#pragma unroll
  for (int ni = 0; ni < 4; ++ni) {
    int colL = wnb + ni * 16 + (lane & 15);
    float bv_ = (colL < 128) ? bq[colL] : bk[colL - 128];
#pragma unroll
    for (int mi = 0; mi < 4; ++mi) {
      int rowb = m0 + wmb + mi * 16 + (lane >> 4) * 4;
#pragma unroll
      for (int r = 0; r < 4; ++r)
        O[(long)(rowb + r) * 256 + colL] = f2bf(acc[mi][ni][r] + bv_);
    }
  }
}

// ------- pass A: scales 2+3 scores + softmax + sub-batch mean (unchanged) -----------
__global__ void __launch_bounds__(256) scores_mean(
    const unsigned short* __restrict__ QK2, const unsigned short* __restrict__ QK3,
    unsigned short* __restrict__ A2P, unsigned short* __restrict__ A3P) {
  __shared__ unsigned short Qs[64 * 64];
  __shared__ unsigned short Ks[256 * 64];
  const int bid = blockIdx.x;
  const unsigned short* QK; unsigned short* Aout; int NS, b, m0idx;
  if (bid < 256) { NS = 4; b = bid >> 2; m0idx = bid & 3; QK = QK3; Aout = A3P; }
  else { int u = bid - 256; NS = 2; b = u >> 2; m0idx = u & 3; QK = QK2; Aout = A2P; }
  const int m0 = m0idx * 64;
  const int t = threadIdx.x, lane = t & 63, w = t >> 6;
  const int r8 = t >> 3, sl = t & 7;
  const float sc = 0.088388347648318447f;
  const float invNS = 1.0f / NS;
  f32x4 avg[16] = {};
  for (int h = 0; h < NS; ++h) {
    const unsigned short* base = QK + ((long)(b * NS + h) << 16);
    f32x4 acc[16] = {};
    for (int kc = 0; kc < 2; ++kc) {
#pragma unroll
      for (int i = 0; i < 2; ++i) {
        int row = i * 32 + r8;
        gl2lds16(base + (long)(m0 + row) * 256 + kc * 64 + (sl ^ (row & 7)) * 8,
                 (char*)Qs + i * 4096 + t * 16);
      }
#pragma unroll
      for (int i = 0; i < 8; ++i) {
        int row = i * 32 + r8;
        gl2lds16(base + (long)row * 256 + 128 + kc * 64 + (sl ^ (row & 7)) * 8,
                 (char*)Ks + i * 4096 + t * 16);
      }
      __syncthreads();
#pragma unroll
      for (int kk = 0; kk < 2; ++kk) {
        const int qrow = w * 16 + (lane & 15);
        const int slot = kk * 4 + (lane >> 4);
        bf16x8 qf = *(const bf16x8*)((char*)Qs + qrow * 128 + 16 * (slot ^ (qrow & 7)));
#pragma unroll
        for (int ni = 0; ni < 16; ++ni) {
          int krow = ni * 16 + (lane & 15);
          bf16x8 kf = *(const bf16x8*)((char*)Ks + krow * 128 + 16 * (slot ^ (krow & 7)));
          acc[ni] = __builtin_amdgcn_mfma_f32_16x16x32_bf16(qf, kf, acc[ni], 0, 0, 0);
        }
      }
      __syncthreads();
    }
#pragma unroll
    for (int r = 0; r < 4; ++r) {
      float mx = -1e30f;
#pragma unroll
      for (int ni = 0; ni < 16; ++ni) mx = fmaxf(mx, acc[ni][r]);
#pragma unroll
      for (int off = 1; off < 16; off <<= 1) mx = fmaxf(mx, __shfl_xor(mx, off, 64));
      float s = 0.0f;
#pragma unroll
      for (int ni = 0; ni < 16; ++ni) {
        float p = __expf((acc[ni][r] - mx) * sc);
        acc[ni][r] = p;
        s += p;
      }
#pragma unroll
      for (int off = 1; off < 16; off <<= 1) s += __shfl_xor(s, off, 64);
      float f = invNS / s;
#pragma unroll
      for (int ni = 0; ni < 16; ++ni) avg[ni][r] += acc[ni][r] * f;
    }
  }
  unsigned short* Of = Aout + (((long)b * 4 + m0idx) * 256 + t) * 64;
#pragma unroll
  for (int r = 0; r < 4; ++r) {
    ushort8 lo, hi;
#pragma unroll
    for (int j = 0; j < 8; ++j) { lo[j] = f2bf(avg[j][r]); hi[j] = f2bf(avg[8 + j][r]); }
    *(ushort8*)(Of + r * 16) = lo;
    *(ushort8*)(Of + r * 16 + 8) = hi;
  }
}

// ------- pass B: scale1 scores + softmax + gate combine -> ATTN + rowsum(attn) ------
__global__ void __launch_bounds__(256) scores1_gate(
    const unsigned short* __restrict__ QK1, const unsigned short* __restrict__ A2P,
    const unsigned short* __restrict__ A3P, unsigned short* __restrict__ ATTN,
    float* __restrict__ RS) {
  __shared__ unsigned short Qs[64 * 64];
  __shared__ unsigned short Ks[256 * 64];
  const int bid = blockIdx.x;
  const int b = bid >> 2, m0 = (bid & 3) * 64;
  const unsigned short* base = QK1 + ((long)b << 16);
  const int t = threadIdx.x, lane = t & 63, w = t >> 6;
  const int r8 = t >> 3, sl = t & 7;
  f32x4 acc[16] = {};
  for (int kc = 0; kc < 2; ++kc) {
#pragma unroll
    for (int i = 0; i < 2; ++i) {
      int row = i * 32 + r8;
      gl2lds16(base + (long)(m0 + row) * 256 + kc * 64 + (sl ^ (row & 7)) * 8,
               (char*)Qs + i * 4096 + t * 16);
    }
#pragma unroll
    for (int i = 0; i < 8; ++i) {
      int row = i * 32 + r8;
      gl2lds16(base + (long)row * 256 + 128 + kc * 64 + (sl ^ (row & 7)) * 8,
               (char*)Ks + i * 4096 + t * 16);
    }
    __syncthreads();
#pragma unroll
    for (int kk = 0; kk < 2; ++kk) {
      const int qrow = w * 16 + (lane & 15);
      const int slot = kk * 4 + (lane >> 4);
      bf16x8 qf = *(const bf16x8*)((char*)Qs + qrow * 128 + 16 * (slot ^ (qrow & 7)));
#pragma unroll
      for (int ni = 0; ni < 16; ++ni) {
        int krow = ni * 16 + (lane & 15);
        bf16x8 kf = *(const bf16x8*)((char*)Ks + krow * 128 + 16 * (slot ^ (krow & 7)));
        acc[ni] = __builtin_amdgcn_mfma_f32_16x16x32_bf16(qf, kf, acc[ni], 0, 0, 0);
      }
    }
    __syncthreads();
  }
  const float sc = 0.088388347648318447f;
#pragma unroll
  for (int r = 0; r < 4; ++r) {
    float mx = -1e30f;
#pragma unroll
    for (int ni = 0; ni < 16; ++ni) mx = fmaxf(mx, acc[ni][r]);
#pragma unroll
    for (int off = 1; off < 16; off <<= 1) mx = fmaxf(mx, __shfl_xor(mx, off, 64));
    float s = 0.0f;
#pragma unroll
    for (int ni = 0; ni < 16; ++ni) {
      float p = __expf((acc[ni][r] - mx) * sc);
      acc[ni][r] = p;
      s += p;
    }
#pragma unroll
    for (int off = 1; off < 16; off <<= 1) s += __shfl_xor(s, off, 64);
    float inv = 1.0f / s;
    long fidx = ((long)bid * 256 + t) * 64 + r * 16;
    ushort8 a2l = *(const ushort8*)(A2P + fidx);
    ushort8 a2h = *(const ushort8*)(A2P + fidx + 8);
    ushort8 a3l = *(const ushort8*)(A3P + fidx);
    ushort8 a3h = *(const ushort8*)(A3P + fidx + 8);
    int row = m0 + w * 16 + (lane >> 4) * 4 + r;
    long roff = ((long)b << 16) + (long)row * 256 + (lane & 15);
    float rsum = 0.0f;
#pragma unroll
    for (int j = 0; j < 8; ++j) {
      float A1 = acc[j][r] * inv;
      float A2 = bf2f(a2l[j]), A3 = bf2f(a3l[j]);
      float m = fmaxf(A1, fmaxf(A2, A3));
      float e1 = __expf(A1 - m), e2 = __expf(A2 - m), e3 = __expf(A3 - m);
      float g = (A1 * e1 + A2 * e2 + A3 * e3) / (e1 + e2 + e3);
      rsum += g;
      ATTN[roff + j * 16] = f2bf(g);
    }
#pragma unroll
    for (int j = 0; j < 8; ++j) {
      float A1 = acc[8 + j][r] * inv;
      float A2 = bf2f(a2h[j]), A3 = bf2f(a3h[j]);
      float m = fmaxf(A1, fmaxf(A2, A3));
      float e1 = __expf(A1 - m), e2 = __expf(A2 - m), e3 = __expf(A3 - m);
      float g = (A1 * e1 + A2 * e2 + A3 * e3) / (e1 + e2 + e3);
      rsum += g;
      ATTN[roff + (8 + j) * 16] = f2bf(g);
    }
#pragma unroll
    for (int off = 1; off < 16; off <<= 1) rsum += __shfl_xor(rsum, off, 64);
    if ((lane & 15) == 0) RS[(b << 8) + row] = rsum;
  }
}

// ------- 8-wave NT GEMM, dbuf. GEO: 0 WIDE(128x256), 1 TALL(256x128), 2 SQ(128x128) -
// BIASMODE: 0 none, 1 per-col, 2 per-row, 3 row-bias + rank1 (bias2[row]*rs[col]).
template <int GEO, int F32OUT, int BIASMODE>
__global__ void __launch_bounds__(512) gemm8(
    const unsigned short* __restrict__ A, const unsigned short* __restrict__ B,
    void* __restrict__ OutV, const float* __restrict__ bias,
    const float* __restrict__ bias2, const float* __restrict__ rsb,
    int lda, int ldb, int K, long astr, long bstr, long ostr, int ldo) {
  constexpr int BM = (GEO == 1) ? 256 : 128;
  constexpr int BN = (GEO == 0) ? 256 : 128;
  constexpr int NA = BM / 64, NB = BN / 64;
  constexpr int NFN = (GEO == 2) ? 2 : 4;
  constexpr int BUFS = (NA + NB) * 8192;
  extern __shared__ char smem[];
  const int t = threadIdx.x, lane = t & 63, wid = t >> 6;
  const int wmb = (GEO == 1) ? (wid >> 1) * 64 : (wid >> 2) * 64;
  const int wnb = (GEO == 1) ? (wid & 1) * 64 : ((GEO == 0) ? (wid & 3) * 64 : (wid & 3) * 32);
  const int m0 = blockIdx.y * BM, n0 = blockIdx.x * BN;
  const int bz = blockIdx.z;
  const unsigned short* Ab = A + (long)bz * astr + (long)m0 * lda;
  const unsigned short* Bb = B + (long)bz * bstr + (long)n0 * ldb;
  const float* rs = (BIASMODE == 3) ? (rsb + (long)bz * 256) : nullptr;
  const int srow = t >> 3, ssl = t & 7;

  auto stage = [&](int buf, int k0) {
    char* s = smem + buf * BUFS;
#pragma unroll
    for (int i = 0; i < NA; ++i) {
      int row = i * 64 + srow;
      gl2lds16(Ab + (long)row * lda + k0 + (ssl ^ (row & 7)) * 8, s + i * 8192 + t * 16);
    }
#pragma unroll
    for (int i = 0; i < NB; ++i) {
      int row = i * 64 + srow;
      gl2lds16(Bb + (long)row * ldb + k0 + (ssl ^ (row & 7)) * 8,
               s + NA * 8192 + i * 8192 + t * 16);
    }
  };

  f32x4 acc[4][NFN] = {};
  stage(0, 0);
  __syncthreads();
  int cur = 0;
  for (int k0 = 0; k0 < K; k0 += 64) {
    if (k0 + 64 < K) stage(cur ^ 1, k0 + 64);
    const char* s = smem + cur * BUFS;
#pragma unroll
    for (int kk = 0; kk < 2; ++kk) {
      const int slot = kk * 4 + (lane >> 4);
      bf16x8 af[4], bfr[NFN];
#pragma unroll
      for (int mi = 0; mi < 4; ++mi) {
        int row = wmb + mi * 16 + (lane & 15);
        af[mi] = *(const bf16x8*)(s + row * 128 + 16 * (slot ^ (row & 7)));
      }
#pragma unroll
      for (int ni = 0; ni < NFN; ++ni) {
        int row = wnb + ni * 16 + (lane & 15);
        bfr[ni] = *(const bf16x8*)(s + NA * 8192 + row * 128 + 16 * (slot ^ (row & 7)));
      }
#pragma unroll
      for (int mi = 0; mi < 4; ++mi)
#pragma unroll
        for (int ni = 0; ni < NFN; ++ni)
          acc[mi][ni] = __builtin_amdgcn_mfma_f32_16x16x32_bf16(af[mi], bfr[ni], acc[mi][ni], 0, 0, 0);
    }
    __syncthreads();
    cur ^= 1;
  }
#pragma unroll
  for (int mi = 0; mi < 4; ++mi) {
    int rowb = m0 + wmb + mi * 16 + (lane >> 4) * 4;
    float rb[4], rb2[4];
#pragma unroll
    for (int r = 0; r < 4; ++r) {
      rb[r] = (BIASMODE >= 2) ? bias[rowb + r] : 0.0f;
      rb2[r] = (BIASMODE == 3) ? bias2[rowb + r] : 0.0f;
    }
#pragma unroll
    for (int ni = 0; ni < NFN; ++ni) {
      int col = n0 + wnb + ni * 16 + (lane & 15);
      float cb = (BIASMODE == 1) ? bias[col] : 0.0f;
      float rsc = (BIASMODE == 3) ? rs[col] : 0.0f;
#pragma unroll
      for (int r = 0; r < 4; ++r) {
        float v = acc[mi][ni][r];
        if constexpr (BIASMODE == 1) v += cb;
        if constexpr (BIASMODE == 2) v += rb[r];
        if constexpr (BIASMODE == 3) v += rb[r] + rb2[r] * rsc;
        if constexpr (F32OUT)
          ((float*)OutV)[(long)bz * ostr + (long)(rowb + r) * ldo + col] = v;
        else
          ((unsigned short*)OutV)[(long)bz * ostr + (long)(rowb + r) * ldo + col] = f2bf(v);
      }
    }
  }
}

// ------------------------------------------------------------------------------------
extern "C" void kernel_launch(void* const* d_in, const int* in_sizes, int n_in,
                              void* d_out, int out_size, void* d_ws, size_t ws_size,
                              hipStream_t stream) {
  (void)in_sizes; (void)n_in; (void)out_size; (void)ws_size;
  const float* x   = (const float*)d_in[0];
  const float* wq1 = (const float*)d_in[1];
  const float* bq1 = (const float*)d_in[2];
  const float* wk1 = (const float*)d_in[3];
  const float* bk1 = (const float*)d_in[4];
  const float* wq2 = (const float*)d_in[5];
  const float* bq2 = (const float*)d_in[6];
  const float* wk2 = (const float*)d_in[7];
  const float* bk2 = (const float*)d_in[8];
  const float* wq3 = (const float*)d_in[9];
  const float* bq3 = (const float*)d_in[10];
  const float* wk3 = (const float*)d_in[11];
  const float* bk3 = (const float*)d_in[12];
  const float* wv  = (const float*)d_in[13];
  const float* bv  = (const float*)d_in[14];
  const float* wo  = (const float*)d_in[15];
  const float* bo  = (const float*)d_in[16];
  char* ws = (char*)d_ws;

  // workspace layout (bytes), peak ~94.4 MB
  unsigned short* XT   = (unsigned short*)(ws + 0);         // [64][256][512] 16.8MB
  unsigned short* WQK1 = (unsigned short*)(ws + 16777216);  // [256][512]
  unsigned short* WQK2 = (unsigned short*)(ws + 17039360);  // [256][256]
  unsigned short* WQK3 = (unsigned short*)(ws + 17170432);  // [256][128]
  unsigned short* WOT  = (unsigned short*)(ws + 17235968);  // [512][512] wo^T
  unsigned short* WVNT = (unsigned short*)(ws + 17760256);  // [512][512] wv row-major
  unsigned short* WVOT = (unsigned short*)(ws + 18284544);  // [512][512] (wv@wo)^T
  float*          BVO  = (float*)(ws + 18808832);           // [512] bv@wo
  float*          RS   = (float*)(ws + 18810880);           // [64][256] rowsum(attn)
  unsigned short* QK1  = (unsigned short*)(ws + 18876416);  // [64][256][256]  (dead after passB)
  unsigned short* QK2  = (unsigned short*)(ws + 27265024);  // [128][256][256] (dead after passA)
  unsigned short* QK3  = (unsigned short*)(ws + 44042240);  // [256][256][256] (dead after passA)
  unsigned short* A2P  = (unsigned short*)(ws + 77596672);  // fragment layout
  unsigned short* A3P  = (unsigned short*)(ws + 85985280);  // fragment layout, end 94,373,888
  unsigned short* ATTN = (unsigned short*)(ws + 44042240);  // [64][256][256] over dead QK3
  unsigned short* XVT  = (unsigned short*)(ws + 18876416);  // [64][512][256] over dead QK1/QK2

  tcast_all<<<dim3(2298), dim3(256), 0, stream>>>(
      x, wq1, wk1, wq2, wk2, wq3, wk3, wv, wo, bv,
      XT, WQK1, WQK2, WQK3, WVNT, WOT, BVO);

  // WVOT[p][s] = sum_t WOT[p][t] * wv[s][t]   (SQ128, 16 blocks, one-time)
  gemm8<2, 0, 0><<<dim3(4, 4, 1), dim3(512), 65536, stream>>>(
      WOT, WVNT, WVOT, nullptr, nullptr, nullptr, 512, 512, 512, 0, 0, 0, 512);

  proj_all8<<<dim3(1, 2, 448), dim3(512), 98304, stream>>>(
      XT, WQK1, WQK2, WQK3, QK1, QK2, QK3, bq1, bk1, bq2, bk2, bq3, bk3);

  scores_mean<<<dim3(512), dim3(256), 0, stream>>>(QK2, QK3, A2P, A3P);
  scores1_gate<<<dim3(256), dim3(256), 0, stream>>>(QK1, A2P, A3P, ATTN, RS);

  // XVT[b][p][d] = sum_s WVOT[p][s] * XT[b][d][s]   (TALL)
  gemm8<1, 0, 0><<<dim3(2, 2, 64), dim3(512), 98304, stream>>>(
      WVOT, XT, XVT, nullptr, nullptr, nullptr, 512, 512, 512, 0, 131072, 131072, 256);
  // out[b][p][c] = sum_d XVT[b][p][d]*ATTN[b][c][d] + bo[p] + BVO[p]*RS[b][c]  (TALL, fp32)
  gemm8<1, 1, 3><<<dim3(2, 2, 64), dim3(512), 98304, stream>>>(
      XVT, ATTN, d_out, bo, BVO, RS, 256, 256, 256, 131072, 65536, 131072, 256);
}

// Round 9
// 117.827 us; speedup vs baseline: 1.2227x; 1.2227x over previous
//
#include <hip/hip_runtime.h>
#include <hip/hip_bf16.h>

// ChannelDeAttention: B=64,S=512,C=256,H=128,P=512
// bf16 MFMA (16x16x32), fp32 accum. 6 launches. XOR-swizzled LDS,
// 2-phase double-buffered GEMMs. WVO = wv@wo fusion (WVOT+BVO computed as
// extra blocks inside proj launch); out = attn@(x^T@WVO + 1⊗bvo) + bo.

typedef __attribute__((ext_vector_type(8))) short bf16x8;
typedef __attribute__((ext_vector_type(4))) float f32x4;
typedef __attribute__((ext_vector_type(8))) unsigned short ushort8;

typedef __attribute__((address_space(1))) void* as1vp;
typedef __attribute__((address_space(3))) void* as3vp;

__device__ __forceinline__ void gl2lds16(const void* g, void* l) {
  __builtin_amdgcn_global_load_lds((as1vp)(void*)g, (as3vp)l, 16, 0, 0);
}

__device__ __forceinline__ float bf2f(unsigned short u) {
  union { unsigned int i; float f; } v; v.i = ((unsigned int)u) << 16; return v.f;
}
__device__ __forceinline__ unsigned short f2bf(float f) {
  union { float f; unsigned int i; } v; v.f = f;
  unsigned int r = v.i + 0x7FFFu + ((v.i >> 16) & 1u);
  return (unsigned short)(r >> 16);
}

// ------- transposes (x + 5 weight mats) + plain wv cast, one launch -----------------
__global__ void __launch_bounds__(256) tcast_all(
    const float* __restrict__ x,
    const float* __restrict__ wq1, const float* __restrict__ wk1,
    const float* __restrict__ wq2, const float* __restrict__ wk2,
    const float* __restrict__ wq3, const float* __restrict__ wk3,
    const float* __restrict__ wv, const float* __restrict__ wo,
    unsigned short* __restrict__ XT,
    unsigned short* __restrict__ W1, unsigned short* __restrict__ W2,
    unsigned short* __restrict__ W3, unsigned short* __restrict__ WVNT,
    unsigned short* __restrict__ WOT) {
  const int bid = blockIdx.x;
  const int t = threadIdx.x;
  if (bid >= 2168) {  // plain-cast wv to bf16 row-major (coalesced)
    long i0 = (long)(bid - 2168) * 2048 + t * 8;
    f32x4 a = *(const f32x4*)(wv + i0);
    f32x4 b = *(const f32x4*)(wv + i0 + 4);
    ushort8 o;
#pragma unroll
    for (int j = 0; j < 4; ++j) { o[j] = f2bf(a[j]); o[4 + j] = f2bf(b[j]); }
    *(ushort8*)(WVNT + i0) = o;
    return;
  }
  __shared__ float lds[64][65];
  const float* S; unsigned short* D; int R, Cc, r0, c0, rowoff = 0;
  if (bid < 2048) {
    int bz = bid >> 5, i = bid & 31;
    S = x + (long)bz * 131072; D = XT + (long)bz * 131072;
    R = 512; Cc = 256; r0 = (i & 7) * 64; c0 = (i >> 3) * 64;
  } else {
    int wb = bid - 2048;
    if (wb < 32) {
      int m = wb >> 4, i = wb & 15;
      S = m ? wk1 : wq1; D = W1; R = 512; Cc = 128;
      r0 = (i & 7) * 64; c0 = (i >> 3) * 64; rowoff = m * 128;
    } else if (wb < 48) {
      int m = (wb - 32) >> 3, i = (wb - 32) & 7;
      S = m ? wk2 : wq2; D = W2; R = 256; Cc = 128;
      r0 = (i & 3) * 64; c0 = (i >> 2) * 64; rowoff = m * 128;
    } else if (wb < 56) {
      int m = (wb - 48) >> 2, i = (wb - 48) & 3;
      S = m ? wk3 : wq3; D = W3; R = 128; Cc = 128;
      r0 = (i & 1) * 64; c0 = (i >> 1) * 64; rowoff = m * 128;
    } else {
      int i = wb - 56; S = wo; D = WOT; R = 512; Cc = 512;
      r0 = (i & 7) * 64; c0 = (i >> 3) * 64;
    }
  }
  const int c = t & 63, rbase = (t >> 6) * 16;
#pragma unroll
  for (int i = 0; i < 16; ++i)
    lds[rbase + i][c] = S[(long)(r0 + rbase + i) * Cc + c0 + c];
  __syncthreads();
  const int rr = (t & 31) * 2, ccb = t >> 5;
#pragma unroll
  for (int j = 0; j < 8; ++j) {
    int cc = ccb + j * 8;
    unsigned int u0 = f2bf(lds[rr][cc]);
    unsigned int u1 = f2bf(lds[rr + 1][cc]);
    *(unsigned int*)(D + (long)(c0 + cc + rowoff) * R + r0 + rr) = u0 | (u1 << 16);
  }
}

// ------- fused Q/K projections + WVOT SQ-gemm blocks + BVO blocks, one launch -------
// grid (1,2,458): z<448 proj; z in [448,456) WVOT (w=(z-448)*2+y); z>=456 BVO.
__global__ void __launch_bounds__(512) proj_all8(
    const unsigned short* __restrict__ XT,
    const unsigned short* __restrict__ W1, const unsigned short* __restrict__ W2,
    const unsigned short* __restrict__ W3,
    const unsigned short* __restrict__ WOT, const unsigned short* __restrict__ WVNT,
    unsigned short* __restrict__ WVOT, float* __restrict__ BVO,
    const float* __restrict__ bv,
    unsigned short* __restrict__ Q1, unsigned short* __restrict__ Q2,
    unsigned short* __restrict__ Q3,
    const float* __restrict__ bq1, const float* __restrict__ bk1,
    const float* __restrict__ bq2, const float* __restrict__ bk2,
    const float* __restrict__ bq3, const float* __restrict__ bk3) {
  extern __shared__ char smem[];
  const int z = blockIdx.z;
  const int t = threadIdx.x, lane = t & 63, wid = t >> 6;

  if (z >= 456) {  // ---- BVO[p] = sum_s bv[s] * WOT[p][s], 4 blocks x 8 waves x 16 p
    int p0 = ((z - 456) * 2 + blockIdx.y) * 128 + wid * 16;
    f32x4 b0 = *(const f32x4*)(bv + lane * 8);
    f32x4 b1 = *(const f32x4*)(bv + lane * 8 + 4);
#pragma unroll
    for (int i = 0; i < 16; ++i) {
      int p = p0 + i;
      bf16x8 wrow = *(const bf16x8*)(WOT + (long)p * 512 + lane * 8);
      float s = 0.0f;
#pragma unroll
      for (int j = 0; j < 4; ++j) {
        s += b0[j] * bf2f((unsigned short)wrow[j]);
        s += b1[j] * bf2f((unsigned short)wrow[4 + j]);
      }
#pragma unroll
      for (int off = 1; off < 64; off <<= 1) s += __shfl_xor(s, off, 64);
      if (lane == 0) BVO[p] = s;
    }
    return;
  }

  if (z >= 448) {  // ---- WVOT[p][s] = sum_t WOT[p][t]*wv[s][t], SQ128 dbuf, 16 blocks
    const int w = (z - 448) * 2 + blockIdx.y;
    const int m0 = (w >> 2) * 128, n0 = (w & 3) * 128;
    const unsigned short* Ab = WOT + (long)m0 * 512;
    const unsigned short* Bb = WVNT + (long)n0 * 512;
    const int wmb = (wid >> 2) * 64, wnb = (wid & 3) * 32;
    const int srow = t >> 3, ssl = t & 7;
    f32x4 acc[4][2] = {};
    auto stageS = [&](int buf, int k0) {
      char* s = smem + buf * 32768;
#pragma unroll
      for (int i = 0; i < 2; ++i) {
        int row = i * 64 + srow;
        gl2lds16(Ab + (long)row * 512 + k0 + (ssl ^ (row & 7)) * 8, s + i * 8192 + t * 16);
        gl2lds16(Bb + (long)row * 512 + k0 + (ssl ^ (row & 7)) * 8, s + 16384 + i * 8192 + t * 16);
      }
    };
    stageS(0, 0);
    __syncthreads();
    int cur = 0;
    for (int k0 = 0; k0 < 512; k0 += 64) {
      if (k0 + 64 < 512) stageS(cur ^ 1, k0 + 64);
      const char* s = smem + cur * 32768;
#pragma unroll
      for (int kk = 0; kk < 2; ++kk) {
        const int slot = kk * 4 + (lane >> 4);
        bf16x8 af[4], bfr[2];
#pragma unroll
        for (int mi = 0; mi < 4; ++mi) {
          int row = wmb + mi * 16 + (lane & 15);
          af[mi] = *(const bf16x8*)(s + row * 128 + 16 * (slot ^ (row & 7)));
        }
#pragma unroll
        for (int ni = 0; ni < 2; ++ni) {
          int row = wnb + ni * 16 + (lane & 15);
          bfr[ni] = *(const bf16x8*)(s + 16384 + row * 128 + 16 * (slot ^ (row & 7)));
        }
#pragma unroll
        for (int mi = 0; mi < 4; ++mi)
#pragma unroll
          for (int ni = 0; ni < 2; ++ni)
            acc[mi][ni] = __builtin_amdgcn_mfma_f32_16x16x32_bf16(af[mi], bfr[ni], acc[mi][ni], 0, 0, 0);
      }
      __syncthreads();
      cur ^= 1;
    }
#pragma unroll
    for (int ni = 0; ni < 2; ++ni) {
      int col = n0 + wnb + ni * 16 + (lane & 15);
#pragma unroll
      for (int mi = 0; mi < 4; ++mi) {
        int rowb = m0 + wmb + mi * 16 + (lane >> 4) * 4;
#pragma unroll
        for (int r = 0; r < 4; ++r)
          WVOT[(long)(rowb + r) * 512 + col] = f2bf(acc[mi][ni][r]);
      }
    }
    return;
  }

  // ---- normal proj path ----
  const unsigned short* Ab; const unsigned short* Bw; unsigned short* O;
  const float *bq, *bk; int K;
  if (z < 64) {
    K = 512; Bw = W1; O = Q1 + (long)z * 65536; bq = bq1; bk = bk1;
    Ab = XT + (long)z * 131072;
  } else if (z < 192) {
    int u = z - 64; K = 256; Bw = W2; O = Q2 + (long)u * 65536; bq = bq2; bk = bk2;
    Ab = XT + (long)(u >> 1) * 131072 + (u & 1) * 256;
  } else {
    int u = z - 192; K = 128; Bw = W3; O = Q3 + (long)u * 65536; bq = bq3; bk = bk3;
    Ab = XT + (long)(u >> 2) * 131072 + (u & 3) * 128;
  }
  const int wmb = (wid >> 2) * 64, wnb = (wid & 3) * 64;
  const int m0 = blockIdx.y * 128;
  Ab += (long)m0 * 512;
  const int srow = t >> 3, ssl = t & 7;

  auto stage = [&](int buf, int k0) {
    char* s = smem + buf * 49152;
#pragma unroll
    for (int i = 0; i < 2; ++i) {
      int row = i * 64 + srow;
      gl2lds16(Ab + (long)row * 512 + k0 + (ssl ^ (row & 7)) * 8, s + i * 8192 + t * 16);
    }
#pragma unroll
    for (int i = 0; i < 4; ++i) {
      int row = i * 64 + srow;
      gl2lds16(Bw + (long)row * K + k0 + (ssl ^ (row & 7)) * 8, s + 16384 + i * 8192 + t * 16);
    }
  };

  f32x4 acc[4][4] = {};
  stage(0, 0);
  __syncthreads();
  int cur = 0;
  for (int k0 = 0; k0 < K; k0 += 64) {
    if (k0 + 64 < K) stage(cur ^ 1, k0 + 64);
    const char* s = smem + cur * 49152;
#pragma unroll
    for (int kk = 0; kk < 2; ++kk) {
      const int slot = kk * 4 + (lane >> 4);
      bf16x8 af[4], bfr[4];
#pragma unroll
      for (int mi = 0; mi < 4; ++mi) {
        int row = wmb + mi * 16 + (lane & 15);
        af[mi] = *(const bf16x8*)(s + row * 128 + 16 * (slot ^ (row & 7)));
      }
#pragma unroll
      for (int ni = 0; ni < 4; ++ni) {
        int row = wnb + ni * 16 + (lane & 15);
        bfr[ni] = *(const bf16x8*)(s + 16384 + row * 128 + 16 * (slot ^ (row & 7)));
      }
#pragma unroll
      for (int mi = 0; mi < 4; ++mi)
#pragma unroll
        for (int ni = 0; ni < 4; ++ni)
          acc[mi][ni] = __builtin_amdgcn_mfma_f32_16x16x32_bf16(af[mi], bfr[ni], acc[mi][ni], 0, 0, 0);
    }
    __syncthreads();
    cur ^= 1;
  }
#pragma unroll
  for (int ni = 0; ni < 4; ++ni) {
    int colL = wnb + ni * 16 + (lane & 15);
    float bv_ = (colL < 128) ? bq[colL] : bk[colL - 128];
#pragma unroll
    for (int mi = 0; mi < 4; ++mi) {
      int rowb = m0 + wmb + mi * 16 + (lane >> 4) * 4;
#pragma unroll
      for (int r = 0; r < 4; ++r)
        O[(long)(rowb + r) * 256 + colL] = f2bf(acc[mi][ni][r] + bv_);
    }
  }
}

// ------- pass A: scales 2+3 scores + softmax + sub-batch mean (unchanged) -----------
__global__ void __launch_bounds__(256) scores_mean(
    const unsigned short* __restrict__ QK2, const unsigned short* __restrict__ QK3,
    unsigned short* __restrict__ A2P, unsigned short* __restrict__ A3P) {
  __shared__ unsigned short Qs[64 * 64];
  __shared__ unsigned short Ks[256 * 64];
  const int bid = blockIdx.x;
  const unsigned short* QK; unsigned short* Aout; int NS, b, m0idx;
  if (bid < 256) { NS = 4; b = bid >> 2; m0idx = bid & 3; QK = QK3; Aout = A3P; }
  else { int u = bid - 256; NS = 2; b = u >> 2; m0idx = u & 3; QK = QK2; Aout = A2P; }
  const int m0 = m0idx * 64;
  const int t = threadIdx.x, lane = t & 63, w = t >> 6;
  const int r8 = t >> 3, sl = t & 7;
  const float sc = 0.088388347648318447f;
  const float invNS = 1.0f / NS;
  f32x4 avg[16] = {};
  for (int h = 0; h < NS; ++h) {
    const unsigned short* base = QK + ((long)(b * NS + h) << 16);
    f32x4 acc[16] = {};
    for (int kc = 0; kc < 2; ++kc) {
#pragma unroll
      for (int i = 0; i < 2; ++i) {
        int row = i * 32 + r8;
        gl2lds16(base + (long)(m0 + row) * 256 + kc * 64 + (sl ^ (row & 7)) * 8,
                 (char*)Qs + i * 4096 + t * 16);
      }
#pragma unroll
      for (int i = 0; i < 8; ++i) {
        int row = i * 32 + r8;
        gl2lds16(base + (long)row * 256 + 128 + kc * 64 + (sl ^ (row & 7)) * 8,
                 (char*)Ks + i * 4096 + t * 16);
      }
      __syncthreads();
#pragma unroll
      for (int kk = 0; kk < 2; ++kk) {
        const int qrow = w * 16 + (lane & 15);
        const int slot = kk * 4 + (lane >> 4);
        bf16x8 qf = *(const bf16x8*)((char*)Qs + qrow * 128 + 16 * (slot ^ (qrow & 7)));
#pragma unroll
        for (int ni = 0; ni < 16; ++ni) {
          int krow = ni * 16 + (lane & 15);
          bf16x8 kf = *(const bf16x8*)((char*)Ks + krow * 128 + 16 * (slot ^ (krow & 7)));
          acc[ni] = __builtin_amdgcn_mfma_f32_16x16x32_bf16(qf, kf, acc[ni], 0, 0, 0);
        }
      }
      __syncthreads();
    }
#pragma unroll
    for (int r = 0; r < 4; ++r) {
      float mx = -1e30f;
#pragma unroll
      for (int ni = 0; ni < 16; ++ni) mx = fmaxf(mx, acc[ni][r]);
#pragma unroll
      for (int off = 1; off < 16; off <<= 1) mx = fmaxf(mx, __shfl_xor(mx, off, 64));
      float s = 0.0f;
#pragma unroll
      for (int ni = 0; ni < 16; ++ni) {
        float p = __expf((acc[ni][r] - mx) * sc);
        acc[ni][r] = p;
        s += p;
      }
#pragma unroll
      for (int off = 1; off < 16; off <<= 1) s += __shfl_xor(s, off, 64);
      float f = invNS / s;
#pragma unroll
      for (int ni = 0; ni < 16; ++ni) avg[ni][r] += acc[ni][r] * f;
    }
  }
  unsigned short* Of = Aout + (((long)b * 4 + m0idx) * 256 + t) * 64;
#pragma unroll
  for (int r = 0; r < 4; ++r) {
    ushort8 lo, hi;
#pragma unroll
    for (int j = 0; j < 8; ++j) { lo[j] = f2bf(avg[j][r]); hi[j] = f2bf(avg[8 + j][r]); }
    *(ushort8*)(Of + r * 16) = lo;
    *(ushort8*)(Of + r * 16 + 8) = hi;
  }
}

// ------- pass B: scale1 scores + softmax + gate combine -> ATTN ---------------------
__global__ void __launch_bounds__(256) scores1_gate(
    const unsigned short* __restrict__ QK1, const unsigned short* __restrict__ A2P,
    const unsigned short* __restrict__ A3P, unsigned short* __restrict__ ATTN) {
  __shared__ unsigned short Qs[64 * 64];
  __shared__ unsigned short Ks[256 * 64];
  const int bid = blockIdx.x;
  const int b = bid >> 2, m0 = (bid & 3) * 64;
  const unsigned short* base = QK1 + ((long)b << 16);
  const int t = threadIdx.x, lane = t & 63, w = t >> 6;
  const int r8 = t >> 3, sl = t & 7;
  f32x4 acc[16] = {};
  for (int kc = 0; kc < 2; ++kc) {
#pragma unroll
    for (int i = 0; i < 2; ++i) {
      int row = i * 32 + r8;
      gl2lds16(base + (long)(m0 + row) * 256 + kc * 64 + (sl ^ (row & 7)) * 8,
               (char*)Qs + i * 4096 + t * 16);
    }
#pragma unroll
    for (int i = 0; i < 8; ++i) {
      int row = i * 32 + r8;
      gl2lds16(base + (long)row * 256 + 128 + kc * 64 + (sl ^ (row & 7)) * 8,
               (char*)Ks + i * 4096 + t * 16);
    }
    __syncthreads();
#pragma unroll
    for (int kk = 0; kk < 2; ++kk) {
      const int qrow = w * 16 + (lane & 15);
      const int slot = kk * 4 + (lane >> 4);
      bf16x8 qf = *(const bf16x8*)((char*)Qs + qrow * 128 + 16 * (slot ^ (qrow & 7)));
#pragma unroll
      for (int ni = 0; ni < 16; ++ni) {
        int krow = ni * 16 + (lane & 15);
        bf16x8 kf = *(const bf16x8*)((char*)Ks + krow * 128 + 16 * (slot ^ (krow & 7)));
        acc[ni] = __builtin_amdgcn_mfma_f32_16x16x32_bf16(qf, kf, acc[ni], 0, 0, 0);
      }
    }
    __syncthreads();
  }
  const float sc = 0.088388347648318447f;
#pragma unroll
  for (int r = 0; r < 4; ++r) {
    float mx = -1e30f;
#pragma unroll
    for (int ni = 0; ni < 16; ++ni) mx = fmaxf(mx, acc[ni][r]);
#pragma unroll
    for (int off = 1; off < 16; off <<= 1) mx = fmaxf(mx, __shfl_xor(mx, off, 64));
    float s = 0.0f;
#pragma unroll
    for (int ni = 0; ni < 16; ++ni) {
      float p = __expf((acc[ni][r] - mx) * sc);
      acc[ni][r] = p;
      s += p;
    }
#pragma unroll
    for (int off = 1; off < 16; off <<= 1) s += __shfl_xor(s, off, 64);
    float inv = 1.0f / s;
    long fidx = ((long)bid * 256 + t) * 64 + r * 16;
    ushort8 a2l = *(const ushort8*)(A2P + fidx);
    ushort8 a2h = *(const ushort8*)(A2P + fidx + 8);
    ushort8 a3l = *(const ushort8*)(A3P + fidx);
    ushort8 a3h = *(const ushort8*)(A3P + fidx + 8);
    int row = m0 + w * 16 + (lane >> 4) * 4 + r;
    long roff = ((long)b << 16) + (long)row * 256 + (lane & 15);
#pragma unroll
    for (int j = 0; j < 8; ++j) {
      float A1 = acc[j][r] * inv;
      float A2 = bf2f(a2l[j]), A3 = bf2f(a3l[j]);
      float m = fmaxf(A1, fmaxf(A2, A3));
      float e1 = __expf(A1 - m), e2 = __expf(A2 - m), e3 = __expf(A3 - m);
      ATTN[roff + j * 16] = f2bf((A1 * e1 + A2 * e2 + A3 * e3) / (e1 + e2 + e3));
    }
#pragma unroll
    for (int j = 0; j < 8; ++j) {
      float A1 = acc[8 + j][r] * inv;
      float A2 = bf2f(a2h[j]), A3 = bf2f(a3h[j]);
      float m = fmaxf(A1, fmaxf(A2, A3));
      float e1 = __expf(A1 - m), e2 = __expf(A2 - m), e3 = __expf(A3 - m);
      ATTN[roff + (8 + j) * 16] = f2bf((A1 * e1 + A2 * e2 + A3 * e3) / (e1 + e2 + e3));
    }
  }
}

// ------- 8-wave TALL(256x128) NT GEMM, dbuf. BIASMODE: 0 none, 2 per-row ------------
template <int F32OUT, int BIASMODE>
__global__ void __launch_bounds__(512) gemm8(
    const unsigned short* __restrict__ A, const unsigned short* __restrict__ B,
    void* __restrict__ OutV, const float* __restrict__ bias,
    int lda, int ldb, int K, long astr, long bstr, long ostr, int ldo) {
  extern __shared__ char smem[];  // per buf 48K: A [256][64]sw + B [128][64]sw
  const int t = threadIdx.x, lane = t & 63, wid = t >> 6;
  const int wmb = (wid >> 1) * 64, wnb = (wid & 1) * 64;
  const int m0 = blockIdx.y * 256, n0 = blockIdx.x * 128;
  const int bz = blockIdx.z;
  const unsigned short* Ab = A + (long)bz * astr + (long)m0 * lda;
  const unsigned short* Bb = B + (long)bz * bstr + (long)n0 * ldb;
  const int srow = t >> 3, ssl = t & 7;

  auto stage = [&](int buf, int k0) {
    char* s = smem + buf * 49152;
#pragma unroll
    for (int i = 0; i < 4; ++i) {
      int row = i * 64 + srow;
      gl2lds16(Ab + (long)row * lda + k0 + (ssl ^ (row & 7)) * 8, s + i * 8192 + t * 16);
    }
#pragma unroll
    for (int i = 0; i < 2; ++i) {
      int row = i * 64 + srow;
      gl2lds16(Bb + (long)row * ldb + k0 + (ssl ^ (row & 7)) * 8,
               s + 32768 + i * 8192 + t * 16);
    }
  };

  f32x4 acc[4][4] = {};
  stage(0, 0);
  __syncthreads();
  int cur = 0;
  for (int k0 = 0; k0 < K; k0 += 64) {
    if (k0 + 64 < K) stage(cur ^ 1, k0 + 64);
    const char* s = smem + cur * 49152;
#pragma unroll
    for (int kk = 0; kk < 2; ++kk) {
      const int slot = kk * 4 + (lane >> 4);
      bf16x8 af[4], bfr[4];
#pragma unroll
      for (int mi = 0; mi < 4; ++mi) {
        int row = wmb + mi * 16 + (lane & 15);
        af[mi] = *(const bf16x8*)(s + row * 128 + 16 * (slot ^ (row & 7)));
      }
#pragma unroll
      for (int ni = 0; ni < 4; ++ni) {
        int row = wnb + ni * 16 + (lane & 15);
        bfr[ni] = *(const bf16x8*)(s + 32768 + row * 128 + 16 * (slot ^ (row & 7)));
      }
#pragma unroll
      for (int mi = 0; mi < 4; ++mi)
#pragma unroll
        for (int ni = 0; ni < 4; ++ni)
          acc[mi][ni] = __builtin_amdgcn_mfma_f32_16x16x32_bf16(af[mi], bfr[ni], acc[mi][ni], 0, 0, 0);
    }
    __syncthreads();
    cur ^= 1;
  }
#pragma unroll
  for (int mi = 0; mi < 4; ++mi) {
    int rowb = m0 + wmb + mi * 16 + (lane >> 4) * 4;
    float rb[4];
#pragma unroll
    for (int r = 0; r < 4; ++r) rb[r] = (BIASMODE == 2) ? bias[rowb + r] : 0.0f;
#pragma unroll
    for (int ni = 0; ni < 4; ++ni) {
      int col = n0 + wnb + ni * 16 + (lane & 15);
#pragma unroll
      for (int r = 0; r < 4; ++r) {
        float v = acc[mi][ni][r] + rb[r];
        if constexpr (F32OUT)
          ((float*)OutV)[(long)bz * ostr + (long)(rowb + r) * ldo + col] = v;
        else
          ((unsigned short*)OutV)[(long)bz * ostr + (long)(rowb + r) * ldo + col] = f2bf(v);
      }
    }
  }
}

// ------------------------------------------------------------------------------------
extern "C" void kernel_launch(void* const* d_in, const int* in_sizes, int n_in,
                              void* d_out, int out_size, void* d_ws, size_t ws_size,
                              hipStream_t stream) {
  (void)in_sizes; (void)n_in; (void)out_size; (void)ws_size;
  const float* x   = (const float*)d_in[0];
  const float* wq1 = (const float*)d_in[1];
  const float* bq1 = (const float*)d_in[2];
  const float* wk1 = (const float*)d_in[3];
  const float* bk1 = (const float*)d_in[4];
  const float* wq2 = (const float*)d_in[5];
  const float* bq2 = (const float*)d_in[6];
  const float* wk2 = (const float*)d_in[7];
  const float* bk2 = (const float*)d_in[8];
  const float* wq3 = (const float*)d_in[9];
  const float* bq3 = (const float*)d_in[10];
  const float* wk3 = (const float*)d_in[11];
  const float* bk3 = (const float*)d_in[12];
  const float* wv  = (const float*)d_in[13];
  const float* bv  = (const float*)d_in[14];
  const float* wo  = (const float*)d_in[15];
  const float* bo  = (const float*)d_in[16];
  char* ws = (char*)d_ws;

  // workspace layout (bytes), peak ~94.4 MB
  unsigned short* XT   = (unsigned short*)(ws + 0);         // [64][256][512] 16.8MB
  unsigned short* WQK1 = (unsigned short*)(ws + 16777216);  // [256][512]
  unsigned short* WQK2 = (unsigned short*)(ws + 17039360);  // [256][256]
  unsigned short* WQK3 = (unsigned short*)(ws + 17170432);  // [256][128]
  unsigned short* WOT  = (unsigned short*)(ws + 17235968);  // [512][512] wo^T
  unsigned short* WVNT = (unsigned short*)(ws + 17760256);  // [512][512] wv row-major
  unsigned short* WVOT = (unsigned short*)(ws + 18284544);  // [512][512] (wv@wo)^T
  float*          BVO  = (float*)(ws + 18808832);           // [512] bv@wo
  unsigned short* QK1  = (unsigned short*)(ws + 18876416);  // [64][256][256]  (dead after passB)
  unsigned short* QK2  = (unsigned short*)(ws + 27265024);  // [128][256][256] (dead after passA)
  unsigned short* QK3  = (unsigned short*)(ws + 44042240);  // [256][256][256] (dead after passA)
  unsigned short* A2P  = (unsigned short*)(ws + 77596672);  // fragment layout
  unsigned short* A3P  = (unsigned short*)(ws + 85985280);  // fragment layout, end 94,373,888
  unsigned short* ATTN = (unsigned short*)(ws + 44042240);  // [64][256][256] over dead QK3
  unsigned short* XVT  = (unsigned short*)(ws + 18876416);  // [64][512][256] over dead QK1/QK2

  tcast_all<<<dim3(2296), dim3(256), 0, stream>>>(
      x, wq1, wk1, wq2, wk2, wq3, wk3, wv, wo,
      XT, WQK1, WQK2, WQK3, WVNT, WOT);

  proj_all8<<<dim3(1, 2, 458), dim3(512), 98304, stream>>>(
      XT, WQK1, WQK2, WQK3, WOT, WVNT, WVOT, BVO, bv,
      QK1, QK2, QK3, bq1, bk1, bq2, bk2, bq3, bk3);

  scores_mean<<<dim3(512), dim3(256), 0, stream>>>(QK2, QK3, A2P, A3P);
  scores1_gate<<<dim3(256), dim3(256), 0, stream>>>(QK1, A2P, A3P, ATTN);

  // XVT[b][p][d] = sum_s WVOT[p][s]*XT[b][d][s] + BVO[p]   (TALL, row-bias)
  gemm8<0, 2><<<dim3(2, 2, 64), dim3(512), 98304, stream>>>(
      WVOT, XT, XVT, BVO, 512, 512, 512, 0, 131072, 131072, 256);
  // out[b][p][c] = sum_d XVT[b][p][d]*ATTN[b][c][d] + bo[p] (TALL, row-bias, fp32)
  gemm8<1, 2><<<dim3(2, 2, 64), dim3(512), 98304, stream>>>(
      XVT, ATTN, d_out, bo, 256, 256, 256, 131072, 65536, 131072, 256);
}